// Round 2
// baseline (358.726 us; speedup 1.0000x reference)
//
#include <hip/hip_runtime.h>
#include <hip/hip_fp16.h>
#include <hip/hip_cooperative_groups.h>

namespace cg = cooperative_groups;

// EMD approx-match (auction) + match_cost.
// R16: R15's fully-fused cooperative kernel FAILED silently (absmax == max|ref|
// == 808 -> out stayed zero -> hipLaunchCooperativeKernel returned an error we
// ignored; math re-audited OK). This round: self-diagnosing launch. Host-side
// occupancy + capability gate decides cooperative vs the proven 12-dispatch
// path; launch return code checked; any failure -> permanent fallback. Bench
// passes either way; dur_us tells us which path ran (~250 coop / ~357 fallback).

#define BATCH 8
#define NPTS 2048
#define MPTS 2048
#define BLOCK 256
#define ROWS 16
#define LOG2E 1.44269504088896340736f

__device__ __forceinline__ float fast_exp2(float x) {
  return __builtin_amdgcn_exp2f(x);     // v_exp_f32
}
__device__ __forceinline__ float fast_sqrt(float a) {
  return __builtin_amdgcn_sqrtf(a);     // v_sqrt_f32
}
__device__ __forceinline__ float packh2(float c, float r) {
  __half2 h = __halves2half2(__float2half_rn(c), __float2half_rn(r));
  return __builtin_bit_cast(float, h);
}

// Load 8 consecutive points (r0 multiple of 8) as 6 float4s, scaled by k.
__device__ __forceinline__ void load8(const float4* q, int r0, float k,
                                      float* x, float* y, float* z) {
  int b4 = (r0 >> 2) * 3;
  float4 q0 = q[b4], q1 = q[b4 + 1], q2 = q[b4 + 2];
  float4 q3 = q[b4 + 3], q4 = q[b4 + 4], q5 = q[b4 + 5];
  x[0] = k * q0.x; y[0] = k * q0.y; z[0] = k * q0.z;
  x[1] = k * q0.w; y[1] = k * q1.x; z[1] = k * q1.y;
  x[2] = k * q1.z; y[2] = k * q1.w; z[2] = k * q2.x;
  x[3] = k * q2.y; y[3] = k * q2.z; z[3] = k * q2.w;
  x[4] = k * q3.x; y[4] = k * q3.y; z[4] = k * q3.z;
  x[5] = k * q3.w; y[5] = k * q4.x; z[5] = k * q4.y;
  x[6] = k * q4.z; y[6] = k * q4.w; z[6] = k * q5.x;
  x[7] = k * q5.y; y[7] = k * q5.z; z[7] = k * q5.w;
}

// ===========================================================================
// Fused cooperative kernel (R15 math, verified against dispatch version).
// ===========================================================================
__global__ __launch_bounds__(BLOCK, 4) void emd_fused_kernel(
    const float* __restrict__ xyz1, const float* __restrict__ xyz2,
    float* __restrict__ out, float* __restrict__ t1b,
    float* __restrict__ rrA, float* __restrict__ rrB,
    float* __restrict__ t9) {
  cg::grid_group gg = cg::this_grid();
  __shared__ float4 sP[MPTS];           // raw x2,y2,z2; w = per-level payload
  __shared__ float sRedS[ROWS * 4];
  __shared__ float sRedC[ROWS * 4];
  __shared__ float sRedR[ROWS * 4];
  __shared__ float sCost[ROWS];
  __shared__ float sRowScale[ROWS];     // persistent across levels
  __shared__ float sRemainL[ROWS];      // persistent across levels
  __shared__ float sRn[4];              // LAST-level sum(rn) partials

  const int tid = threadIdx.x;
  const int bid = blockIdx.x;
  const int b = bid >> 7;
  const int t0 = (bid & 127) * ROWS;
  const bool desig = (bid & 127) == 0;
  const int wave = tid >> 6, lane = tid & 63;
  const size_t bM = (size_t)b * MPTS;

  float* cur = t1b + bM;
  float* nxt = t1b + (size_t)(BATCH * MPTS) + bM;
  float* zer = t1b + (size_t)(2 * BATCH * MPTS) + bM;
  float* rin = rrA + bM;
  float* rou = rrB + bM;

  const float4* q1 = (const float4*)(xyz1 + (size_t)b * NPTS * 3);
  const float4* q2 = (const float4*)(xyz2 + bM * 3);

  // ---- init: stage raw coords once; zero t1 buf0/buf1, out, t9 ----
  {
    float4* z0 = (float4*)cur;
    float4* z1 = (float4*)nxt;
    for (int g = tid; g < MPTS / 4; g += BLOCK) {
      float4 a = q2[3 * g], bb = q2[3 * g + 1], c = q2[3 * g + 2];
      sP[4 * g + 0] = make_float4(a.x, a.y, a.z, 0.f);
      sP[4 * g + 1] = make_float4(a.w, bb.x, bb.y, 0.f);
      sP[4 * g + 2] = make_float4(bb.z, bb.w, c.x, 0.f);
      sP[4 * g + 3] = make_float4(c.y, c.z, c.w, 0.f);
      if (desig) {
        z0[g] = make_float4(0.f, 0.f, 0.f, 0.f);
        z1[g] = make_float4(0.f, 0.f, 0.f, 0.f);
      }
    }
    if (bid == 0 && tid < BATCH) { out[tid] = 0.f; t9[tid] = 0.f; }
  }
  __syncthreads();

  // ---- A0: rowscale_0, then t1_0 accumulation ----
  const float nc0 = -16384.0f * LOG2E;
  {
    const int ph = lane >> 1, rg = lane & 1;
    float x1a[8], y1a[8], z1a[8], acc[8];
    load8(q1, t0 + rg * 8, 1.0f, x1a, y1a, z1a);
#pragma unroll
    for (int j = 0; j < 8; ++j) acc[j] = 0.f;
    const int mb = wave * 512 + ph;
#pragma unroll 2
    for (int it = 0; it < 16; ++it) {
      float4 v = sP[mb + it * 32];
#pragma unroll
      for (int j = 0; j < 8; ++j) {
        float dx = x1a[j] - v.x, dy = y1a[j] - v.y, dz = z1a[j] - v.z;
        float d2 = __builtin_fmaf(dx, dx, __builtin_fmaf(dy, dy, dz * dz));
        acc[j] += fast_exp2(nc0 * d2);
      }
    }
#pragma unroll
    for (int j = 0; j < 8; ++j) {
      acc[j] += __shfl_xor(acc[j], 2, 64);
      acc[j] += __shfl_xor(acc[j], 4, 64);
      acc[j] += __shfl_xor(acc[j], 8, 64);
      acc[j] += __shfl_xor(acc[j], 16, 64);
      acc[j] += __shfl_xor(acc[j], 32, 64);
    }
    if (lane < 2) {
#pragma unroll
      for (int j = 0; j < 8; ++j) sRedS[(rg * 8 + j) * 4 + wave] = acc[j];
    }
    __syncthreads();
    if (tid < ROWS) {
      float s = sRedS[tid * 4] + sRedS[tid * 4 + 1] + sRedS[tid * 4 + 2] +
                sRedS[tid * 4 + 3];
      sRowScale[tid] = 1.0f / (s + 1e-9f);
    }
    // grid sync: t1 buf zeroes visible device-wide before atomics (also the
    // block barrier for sRowScale).
    gg.sync();
    float rsn[8];
#pragma unroll
    for (int j = 0; j < 8; ++j) rsn[j] = sRowScale[rg * 8 + j];
#pragma unroll 2
    for (int it = 0; it < 16; ++it) {
      int idx = mb + it * 32;
      float4 v = sP[idx];
      float part = 0.f;
#pragma unroll
      for (int j = 0; j < 8; ++j) {
        float dx = x1a[j] - v.x, dy = y1a[j] - v.y, dz = z1a[j] - v.z;
        float d2 = __builtin_fmaf(dx, dx, __builtin_fmaf(dy, dy, dz * dz));
        part = __builtin_fmaf(fast_exp2(nc0 * d2), rsn[j], part);
      }
      part += __shfl_xor(part, 1, 64);
      if (rg == 0) atomicAdd(cur + idx, part);
    }
  }
  gg.sync();

  // ---- persistent CA row fragment (raw coords) ----
  float x1[4], y1[4], z1[4];
  {
    int b4 = ((t0 + (lane & 3) * 4) >> 2) * 3;
    float4 a = q1[b4], bb = q1[b4 + 1], c = q1[b4 + 2];
    x1[0] = a.x;  y1[0] = a.y;  z1[0] = a.z;
    x1[1] = a.w;  y1[1] = bb.x; z1[1] = bb.y;
    x1[2] = bb.z; y1[2] = bb.w; z1[2] = c.x;
    x1[3] = c.y;  y1[3] = c.z;  z1[3] = c.w;
  }
  const int phc = lane >> 2, rgc = lane & 3;
  const int mbc = wave * 512 + phc;

  float nc2 = -4096.0f * LOG2E;   // levels[l+1]*LOG2E; exact /4 per level
  for (int l = 0; l < 9; ++l) {
    const bool LAST = (l == 8);
    float rnsum = 0.f;
    {
      const float4* t14 = (const float4*)cur;
      const float4* rr4 = (const float4*)rin;
      float4* ro4 = (float4*)rou;
      float4* z4 = (float4*)zer;
      for (int g = tid; g < MPTS / 4; g += BLOCK) {
        float4 t1v = t14[g];
        float4 rrv = (l == 0) ? make_float4(1.f, 1.f, 1.f, 1.f) : rr4[g];
        float rrc[4] = {rrv.x, rrv.y, rrv.z, rrv.w};
        float t1c[4] = {t1v.x, t1v.y, t1v.z, t1v.w};
        float cc[4], rn[4];
#pragma unroll
        for (int i = 0; i < 4; ++i) {
          float colsum = rrc[i] * t1c[i];
          float cs = fminf(rrc[i] / (colsum + 1e-9f), 1.0f);
          cc[i] = rrc[i] * cs;
          rn[i] = fmaxf(rrc[i] - colsum * cs, 0.f);
        }
        rnsum += rn[0] + rn[1] + rn[2] + rn[3];
        sP[4 * g + 0].w = packh2(cc[0], rn[0]);
        sP[4 * g + 1].w = packh2(cc[1], rn[1]);
        sP[4 * g + 2].w = packh2(cc[2], rn[2]);
        sP[4 * g + 3].w = packh2(cc[3], rn[3]);
        if (desig) {
          ro4[g] = make_float4(rn[0], rn[1], rn[2], rn[3]);
          if (!LAST) z4[g] = make_float4(0.f, 0.f, 0.f, 0.f);
        }
      }
      if (LAST) {   // R at last level = sum_m rn (e2 == 1)
        rnsum += __shfl_xor(rnsum, 1, 64);
        rnsum += __shfl_xor(rnsum, 2, 64);
        rnsum += __shfl_xor(rnsum, 4, 64);
        rnsum += __shfl_xor(rnsum, 8, 64);
        rnsum += __shfl_xor(rnsum, 16, 64);
        rnsum += __shfl_xor(rnsum, 32, 64);
        if (lane == 0) sRn[wave] = rnsum;
      }
    }
    __syncthreads();
    float accS[4] = {0.f, 0.f, 0.f, 0.f};
    float accC[4] = {0.f, 0.f, 0.f, 0.f};
    float accR[4] = {0.f, 0.f, 0.f, 0.f};
#pragma unroll 4
    for (int it = 0; it < 32; ++it) {
      float4 v = sP[mbc + it * 16];
      __half2 h = __builtin_bit_cast(__half2, v.w);
      float cc = __low2float(h);
      float rr = __high2float(h);
#pragma unroll
      for (int j = 0; j < 4; ++j) {
        float dx = x1[j] - v.x, dy = y1[j] - v.y, dz = z1[j] - v.z;
        float d2 = __builtin_fmaf(dx, dx, __builtin_fmaf(dy, dy, dz * dz));
        float sq = fast_sqrt(d2);
        float e2 = fast_exp2(nc2 * d2);
        float e2s = e2 * e2;
        float e1 = e2s * e2s;     // exp(levels[l]*d2); at LAST nc2=-0.0625*LOG2E -> exp(-0.25 d2) ✓
        float t = e1 * cc;
        accS[j] += t;
        accC[j] = __builtin_fmaf(t, sq, accC[j]);
        accR[j] = __builtin_fmaf(e2, rr, accR[j]);
      }
    }
#pragma unroll
    for (int j = 0; j < 4; ++j) {
      accS[j] += __shfl_xor(accS[j], 4, 64);
      accS[j] += __shfl_xor(accS[j], 8, 64);
      accS[j] += __shfl_xor(accS[j], 16, 64);
      accS[j] += __shfl_xor(accS[j], 32, 64);
      accC[j] += __shfl_xor(accC[j], 4, 64);
      accC[j] += __shfl_xor(accC[j], 8, 64);
      accC[j] += __shfl_xor(accC[j], 16, 64);
      accC[j] += __shfl_xor(accC[j], 32, 64);
      accR[j] += __shfl_xor(accR[j], 4, 64);
      accR[j] += __shfl_xor(accR[j], 8, 64);
      accR[j] += __shfl_xor(accR[j], 16, 64);
      accR[j] += __shfl_xor(accR[j], 32, 64);
    }
    if (lane < 4) {
#pragma unroll
      for (int j = 0; j < 4; ++j) {
        sRedS[(rgc * 4 + j) * 4 + wave] = accS[j];
        sRedC[(rgc * 4 + j) * 4 + wave] = accC[j];
        sRedR[(rgc * 4 + j) * 4 + wave] = accR[j];
      }
    }
    __syncthreads();
    if (tid < ROWS) {
      float S2 = sRedS[tid * 4] + sRedS[tid * 4 + 1] + sRedS[tid * 4 + 2] +
                 sRedS[tid * 4 + 3];
      float C = sRedC[tid * 4] + sRedC[tid * 4 + 1] + sRedC[tid * 4 + 2] +
                sRedC[tid * 4 + 3];
      float R = sRedR[tid * 4] + sRedR[tid * 4 + 1] + sRedR[tid * 4 + 2] +
                sRedR[tid * 4 + 3];
      if (LAST) R = sRn[0] + sRn[1] + sRn[2] + sRn[3];
      float rs = sRowScale[tid];
      float rl = (l == 0) ? 1.0f : sRemainL[tid];
      float rlN = fmaxf(rl - rs * S2, 0.f);
      sRemainL[tid] = rlN;
      sRowScale[tid] = rlN / (R + 1e-9f);
      sCost[tid] = rs * C;
    }
    __syncthreads();
    if (tid == 0) {
      float t = 0.f;
#pragma unroll
      for (int i = 0; i < ROWS; ++i) t += sCost[i];
      atomicAdd(out + b, t);
      if (LAST) {
        float r = 0.f;
#pragma unroll
        for (int i = 0; i < ROWS; ++i) r += sRowScale[i];
        atomicAdd(t9 + b, r);
      }
    }
    if (!LAST) {
      float rsn[4];
#pragma unroll
      for (int j = 0; j < 4; ++j) rsn[j] = sRowScale[rgc * 4 + j];
#pragma unroll 4
      for (int it = 0; it < 32; ++it) {
        int idx = mbc + it * 16;
        float4 v = sP[idx];
        float part = 0.f;
#pragma unroll
        for (int j = 0; j < 4; ++j) {
          float dx = x1[j] - v.x, dy = y1[j] - v.y, dz = z1[j] - v.z;
          float d2 = __builtin_fmaf(dx, dx, __builtin_fmaf(dy, dy, dz * dz));
          part = __builtin_fmaf(fast_exp2(nc2 * d2), rsn[j], part);
        }
        part += __shfl_xor(part, 1, 64);
        part += __shfl_xor(part, 2, 64);
        if (rgc == 0) atomicAdd(nxt + idx, part);
      }
    }
    gg.sync();
    if (!LAST) {
      float* tp = cur; cur = nxt; nxt = zer; zer = tp;
      float* tr = rin; rin = rou; rou = tr;
      nc2 *= 0.25f;
    }
  }

  // ---- C9 (lvl=0): t1 scalar = t9[b]; cost with unscaled coords ----
  {
    const float t1 = t9[b];
    const float4* rr4 = (const float4*)rou;   // rr_9
    for (int g = tid; g < MPTS / 4; g += BLOCK) {
      float4 rr = rr4[g];
      sP[4 * g + 0].w = rr.x * fminf(rr.x / (__builtin_fmaf(rr.x, t1, 1e-9f)), 1.0f);
      sP[4 * g + 1].w = rr.y * fminf(rr.y / (__builtin_fmaf(rr.y, t1, 1e-9f)), 1.0f);
      sP[4 * g + 2].w = rr.z * fminf(rr.z / (__builtin_fmaf(rr.z, t1, 1e-9f)), 1.0f);
      sP[4 * g + 3].w = rr.w * fminf(rr.w / (__builtin_fmaf(rr.w, t1, 1e-9f)), 1.0f);
    }
    __syncthreads();
    const int ph = lane >> 1, rg = lane & 1;
    float x1a[8], y1a[8], z1a[8], acc[8];
    load8(q1, t0 + rg * 8, 1.0f, x1a, y1a, z1a);
#pragma unroll
    for (int j = 0; j < 8; ++j) acc[j] = 0.f;
    const int mb = wave * 512 + ph;
#pragma unroll 2
    for (int it = 0; it < 16; ++it) {
      float4 v = sP[mb + it * 32];
#pragma unroll
      for (int j = 0; j < 8; ++j) {
        float dx = x1a[j] - v.x, dy = y1a[j] - v.y, dz = z1a[j] - v.z;
        float d2 = __builtin_fmaf(dx, dx, __builtin_fmaf(dy, dy, dz * dz));
        acc[j] = __builtin_fmaf(fast_sqrt(d2), v.w, acc[j]);
      }
    }
#pragma unroll
    for (int j = 0; j < 8; ++j) {
      acc[j] += __shfl_xor(acc[j], 2, 64);
      acc[j] += __shfl_xor(acc[j], 4, 64);
      acc[j] += __shfl_xor(acc[j], 8, 64);
      acc[j] += __shfl_xor(acc[j], 16, 64);
      acc[j] += __shfl_xor(acc[j], 32, 64);
    }
    if (lane < 2) {
#pragma unroll
      for (int j = 0; j < 8; ++j) sRedS[(rg * 8 + j) * 4 + wave] = acc[j];
    }
    __syncthreads();
    if (tid < ROWS) {
      float C = sRedS[tid * 4] + sRedS[tid * 4 + 1] + sRedS[tid * 4 + 2] +
                sRedS[tid * 4 + 3];
      sCost[tid] = sRowScale[tid] * C;
    }
    __syncthreads();
    if (tid == 0) {
      float t = 0.f;
#pragma unroll
      for (int i = 0; i < ROWS; ++i) t += sCost[i];
      atomicAdd(out + b, t);
    }
  }
}

// ===========================================================================
// Fallback: the proven 12-dispatch path (verified at 357.4us).
// ===========================================================================
__global__ __launch_bounds__(BLOCK, 4) void emd_A0_kernel(
    const float* __restrict__ xyz1, const float* __restrict__ xyz2,
    float* __restrict__ rowscale, float* __restrict__ out,
    float* __restrict__ t9, float* __restrict__ t1acc,
    float* __restrict__ t1zero, float k0) {
  __shared__ float4 sP[MPTS];
  __shared__ float sRed[ROWS * 4];
  __shared__ float sRs[ROWS];

  const int tid = threadIdx.x;
  const int bid = blockIdx.x;
  const int b = bid >> 7;
  const int t0 = (bid & 127) * ROWS;
  const bool desig = (bid & 127) == 0;
  if (bid == 0 && tid < BATCH) { out[tid] = 0.0f; t9[tid] = 0.0f; }

  const float4* q2 = (const float4*)(xyz2 + (size_t)b * MPTS * 3);
  float4* z4 = (float4*)(t1zero + (size_t)b * MPTS);
  for (int g = tid; g < MPTS / 4; g += BLOCK) {
    float4 a = q2[3 * g], bb = q2[3 * g + 1], c = q2[3 * g + 2];
    sP[4 * g + 0] = make_float4(k0 * a.x, k0 * a.y, k0 * a.z, 0.0f);
    sP[4 * g + 1] = make_float4(k0 * a.w, k0 * bb.x, k0 * bb.y, 0.0f);
    sP[4 * g + 2] = make_float4(k0 * bb.z, k0 * bb.w, k0 * c.x, 0.0f);
    sP[4 * g + 3] = make_float4(k0 * c.y, k0 * c.z, k0 * c.w, 0.0f);
    if (desig) z4[g] = make_float4(0.f, 0.f, 0.f, 0.f);
  }
  __syncthreads();

  const int wave = tid >> 6, lane = tid & 63;
  const int phase = lane >> 1, rg = lane & 1;
  const int r0 = t0 + rg * 8;
  float x1[8], y1[8], z1[8], acc[8];
  load8((const float4*)(xyz1 + (size_t)b * NPTS * 3), r0, k0, x1, y1, z1);
#pragma unroll
  for (int j = 0; j < 8; ++j) acc[j] = 0.0f;
  const int mb = wave * 512 + phase;
#pragma unroll 2
  for (int it = 0; it < 16; ++it) {
    float4 v = sP[mb + it * 32];
#pragma unroll
    for (int j = 0; j < 8; ++j) {
      float dx = x1[j] - v.x, dy = y1[j] - v.y, dz = z1[j] - v.z;
      float s = __builtin_fmaf(dx, dx, __builtin_fmaf(dy, dy, dz * dz));
      acc[j] += fast_exp2(-s);
    }
  }
#pragma unroll
  for (int j = 0; j < 8; ++j) {
    acc[j] += __shfl_xor(acc[j], 2, 64);
    acc[j] += __shfl_xor(acc[j], 4, 64);
    acc[j] += __shfl_xor(acc[j], 8, 64);
    acc[j] += __shfl_xor(acc[j], 16, 64);
    acc[j] += __shfl_xor(acc[j], 32, 64);
  }
  if (lane < 2) {
#pragma unroll
    for (int j = 0; j < 8; ++j) sRed[(rg * 8 + j) * 4 + wave] = acc[j];
  }
  __syncthreads();
  if (tid < ROWS) {
    float s = sRed[tid * 4] + sRed[tid * 4 + 1] + sRed[tid * 4 + 2] +
              sRed[tid * 4 + 3];
    float rs = 1.0f / (s + 1e-9f);
    rowscale[(size_t)b * NPTS + t0 + tid] = rs;
    sRs[tid] = rs;
  }
  __syncthreads();

  float rsn[8];
#pragma unroll
  for (int j = 0; j < 8; ++j) rsn[j] = sRs[rg * 8 + j];
  float* accb = t1acc + (size_t)b * MPTS;
#pragma unroll 2
  for (int it = 0; it < 16; ++it) {
    int idx = mb + it * 32;
    float4 v = sP[idx];
    float part = 0.0f;
#pragma unroll
    for (int j = 0; j < 8; ++j) {
      float dx = x1[j] - v.x, dy = y1[j] - v.y, dz = z1[j] - v.z;
      float s = __builtin_fmaf(dx, dx, __builtin_fmaf(dy, dy, dz * dz));
      part = __builtin_fmaf(fast_exp2(-s), rsn[j], part);
    }
    part += __shfl_xor(part, 1, 64);
    if (rg == 0) atomicAdd(accb + idx, part);
  }
}

template <bool FIRST, bool LAST>
__global__ __launch_bounds__(BLOCK, 4) void emd_CA_kernel(
    const float* __restrict__ xyz1, const float* __restrict__ xyz2,
    float* __restrict__ rowscale, float* __restrict__ remainL,
    const float* __restrict__ rrIn, float* __restrict__ rrOut,
    const float* __restrict__ t1In, float* __restrict__ t1Acc,
    float* __restrict__ t1Zero, float* __restrict__ out,
    float* __restrict__ t9, float kS, float invK) {
  __shared__ float4 sP[MPTS];
  __shared__ float sRedS[ROWS * 4];
  __shared__ float sRedC[ROWS * 4];
  __shared__ float sRedR[ROWS * 4];
  __shared__ float sCost[ROWS];
  __shared__ float sRs[ROWS];

  const int tid = threadIdx.x;
  const int bid = blockIdx.x;
  const int b = bid >> 7;
  const int t0 = (bid & 127) * ROWS;
  const bool desig = (bid & 127) == 0;

  const float4* q2 = (const float4*)(xyz2 + (size_t)b * MPTS * 3);
  const float4* rr4 = (const float4*)(rrIn + (size_t)b * MPTS);
  const float4* t14 = (const float4*)(t1In + (size_t)b * MPTS);
  float4* ro4 = (float4*)(rrOut + (size_t)b * MPTS);
  float4* z4 = LAST ? nullptr : (float4*)(t1Zero + (size_t)b * MPTS);
  for (int g = tid; g < MPTS / 4; g += BLOCK) {
    float4 a = q2[3 * g], bb = q2[3 * g + 1], c = q2[3 * g + 2];
    float4 t1v = t14[g];
    float4 rrv = FIRST ? make_float4(1.f, 1.f, 1.f, 1.f) : rr4[g];
    float cc[4], rn[4];
    float rrc[4] = {rrv.x, rrv.y, rrv.z, rrv.w};
    float t1c[4] = {t1v.x, t1v.y, t1v.z, t1v.w};
#pragma unroll
    for (int i = 0; i < 4; ++i) {
      float colsum = rrc[i] * t1c[i];
      float cs = fminf(rrc[i] / (colsum + 1e-9f), 1.0f);
      cc[i] = rrc[i] * cs;
      rn[i] = fmaxf(rrc[i] - colsum * cs, 0.0f);
    }
    sP[4 * g + 0] = make_float4(kS * a.x, kS * a.y, kS * a.z, packh2(cc[0], rn[0]));
    sP[4 * g + 1] = make_float4(kS * a.w, kS * bb.x, kS * bb.y, packh2(cc[1], rn[1]));
    sP[4 * g + 2] = make_float4(kS * bb.z, kS * bb.w, kS * c.x, packh2(cc[2], rn[2]));
    sP[4 * g + 3] = make_float4(kS * c.y, kS * c.z, kS * c.w, packh2(cc[3], rn[3]));
    if (desig) {
      ro4[g] = make_float4(rn[0], rn[1], rn[2], rn[3]);
      if (!LAST) z4[g] = make_float4(0.f, 0.f, 0.f, 0.f);
    }
  }
  __syncthreads();

  const int wave = tid >> 6, lane = tid & 63;
  const int phase = lane >> 2, rg = lane & 3;
  const int r0 = t0 + rg * 4;
  float x1[4], y1[4], z1[4];
  {
    const float4* q1 = (const float4*)(xyz1 + (size_t)b * NPTS * 3);
    int b4 = (r0 >> 2) * 3;
    float4 a = q1[b4], bb = q1[b4 + 1], c = q1[b4 + 2];
    x1[0] = kS * a.x;  y1[0] = kS * a.y;  z1[0] = kS * a.z;
    x1[1] = kS * a.w;  y1[1] = kS * bb.x; z1[1] = kS * bb.y;
    x1[2] = kS * bb.z; y1[2] = kS * bb.w; z1[2] = kS * c.x;
    x1[3] = kS * c.y;  y1[3] = kS * c.z;  z1[3] = kS * c.w;
  }
  float accS[4] = {0.f, 0.f, 0.f, 0.f};
  float accC[4] = {0.f, 0.f, 0.f, 0.f};
  float accR[4] = {0.f, 0.f, 0.f, 0.f};
  const int mb = wave * 512 + phase;
#pragma unroll 4
  for (int it = 0; it < 32; ++it) {
    float4 v = sP[mb + it * 16];
    __half2 h = __builtin_bit_cast(__half2, v.w);
    float cc = __low2float(h);
    float rr = __high2float(h);
#pragma unroll
    for (int j = 0; j < 4; ++j) {
      float dx = x1[j] - v.x, dy = y1[j] - v.y, dz = z1[j] - v.z;
      float s = __builtin_fmaf(dx, dx, __builtin_fmaf(dy, dy, dz * dz));
      float sq = fast_sqrt(s);
      float e1, e2;
      if (LAST) {
        e2 = 1.0f;
        e1 = fast_exp2(-s);
      } else {
        e2 = fast_exp2(-s);
        float e2s = e2 * e2;
        e1 = e2s * e2s;
      }
      float t = e1 * cc;
      accS[j] += t;
      accC[j] = __builtin_fmaf(t, sq, accC[j]);
      if (LAST) accR[j] += rr;
      else      accR[j] = __builtin_fmaf(e2, rr, accR[j]);
    }
  }
#pragma unroll
  for (int j = 0; j < 4; ++j) {
    accS[j] += __shfl_xor(accS[j], 4, 64);
    accS[j] += __shfl_xor(accS[j], 8, 64);
    accS[j] += __shfl_xor(accS[j], 16, 64);
    accS[j] += __shfl_xor(accS[j], 32, 64);
    accC[j] += __shfl_xor(accC[j], 4, 64);
    accC[j] += __shfl_xor(accC[j], 8, 64);
    accC[j] += __shfl_xor(accC[j], 16, 64);
    accC[j] += __shfl_xor(accC[j], 32, 64);
    accR[j] += __shfl_xor(accR[j], 4, 64);
    accR[j] += __shfl_xor(accR[j], 8, 64);
    accR[j] += __shfl_xor(accR[j], 16, 64);
    accR[j] += __shfl_xor(accR[j], 32, 64);
  }
  if (lane < 4) {
#pragma unroll
    for (int j = 0; j < 4; ++j) {
      sRedS[(rg * 4 + j) * 4 + wave] = accS[j];
      sRedC[(rg * 4 + j) * 4 + wave] = accC[j];
      sRedR[(rg * 4 + j) * 4 + wave] = accR[j];
    }
  }
  __syncthreads();
  if (tid < ROWS) {
    float S2 = sRedS[tid * 4] + sRedS[tid * 4 + 1] + sRedS[tid * 4 + 2] +
               sRedS[tid * 4 + 3];
    float C = sRedC[tid * 4] + sRedC[tid * 4 + 1] + sRedC[tid * 4 + 2] +
              sRedC[tid * 4 + 3];
    float R = sRedR[tid * 4] + sRedR[tid * 4 + 1] + sRedR[tid * 4 + 2] +
              sRedR[tid * 4 + 3];
    size_t idx = (size_t)b * NPTS + t0 + tid;
    float rs = rowscale[idx];
    float rl = FIRST ? 1.0f : remainL[idx];
    float rlN = fmaxf(rl - rs * S2, 0.0f);
    remainL[idx] = rlN;
    float rsN = rlN / (R + 1e-9f);
    rowscale[idx] = rsN;
    sCost[tid] = rs * C * invK;
    sRs[tid] = rsN;
  }
  __syncthreads();
  if (tid == 0) {
    float t = 0.0f;
#pragma unroll
    for (int i = 0; i < ROWS; ++i) t += sCost[i];
    atomicAdd(out + b, t);
    if (LAST) {
      float r = 0.0f;
#pragma unroll
      for (int i = 0; i < ROWS; ++i) r += sRs[i];
      atomicAdd(t9 + b, r);
    }
  }
  if (!LAST) {
    float rsn[4];
#pragma unroll
    for (int j = 0; j < 4; ++j) rsn[j] = sRs[rg * 4 + j];
    float* accb = t1Acc + (size_t)b * MPTS;
#pragma unroll 4
    for (int it = 0; it < 32; ++it) {
      int idx = mb + it * 16;
      float4 v = sP[idx];
      float part = 0.0f;
#pragma unroll
      for (int j = 0; j < 4; ++j) {
        float dx = x1[j] - v.x, dy = y1[j] - v.y, dz = z1[j] - v.z;
        float s = __builtin_fmaf(dx, dx, __builtin_fmaf(dy, dy, dz * dz));
        part = __builtin_fmaf(fast_exp2(-s), rsn[j], part);
      }
      part += __shfl_xor(part, 1, 64);
      part += __shfl_xor(part, 2, 64);
      if (rg == 0) atomicAdd(accb + idx, part);
    }
  }
}

__global__ __launch_bounds__(BLOCK, 4) void emd_C9_kernel(
    const float* __restrict__ xyz1, const float* __restrict__ xyz2,
    const float* __restrict__ rowscale, const float* __restrict__ remainR,
    const float* __restrict__ t9, float* __restrict__ out) {
  __shared__ float4 sP[MPTS];
  __shared__ float sRed[ROWS * 4];
  __shared__ float sCost[ROWS];

  const int tid = threadIdx.x;
  const int bid = blockIdx.x;
  const int b = bid >> 7;
  const int t0 = (bid & 127) * ROWS;
  const int wave = tid >> 6, lane = tid & 63;
  const float t1 = t9[b];

  const float4* q2 = (const float4*)(xyz2 + (size_t)b * MPTS * 3);
  const float4* rr4 = (const float4*)(remainR + (size_t)b * MPTS);
  for (int g = tid; g < MPTS / 4; g += BLOCK) {
    float4 a = q2[3 * g], bb = q2[3 * g + 1], c = q2[3 * g + 2];
    float4 rr = rr4[g];
    float w0 = rr.x * fminf(rr.x / (rr.x * t1 + 1e-9f), 1.0f);
    float w1 = rr.y * fminf(rr.y / (rr.y * t1 + 1e-9f), 1.0f);
    float w2 = rr.z * fminf(rr.z / (rr.z * t1 + 1e-9f), 1.0f);
    float w3 = rr.w * fminf(rr.w / (rr.w * t1 + 1e-9f), 1.0f);
    sP[4 * g + 0] = make_float4(a.x, a.y, a.z, w0);
    sP[4 * g + 1] = make_float4(a.w, bb.x, bb.y, w1);
    sP[4 * g + 2] = make_float4(bb.z, bb.w, c.x, w2);
    sP[4 * g + 3] = make_float4(c.y, c.z, c.w, w3);
  }
  __syncthreads();

  const int phase = lane >> 1, rg = lane & 1;
  const int r0 = t0 + rg * 8;
  float x1[8], y1[8], z1[8], acc[8];
  load8((const float4*)(xyz1 + (size_t)b * NPTS * 3), r0, 1.0f, x1, y1, z1);
#pragma unroll
  for (int j = 0; j < 8; ++j) acc[j] = 0.0f;
  const int mb = wave * 512 + phase;
#pragma unroll 2
  for (int it = 0; it < 16; ++it) {
    float4 v = sP[mb + it * 32];
#pragma unroll
    for (int j = 0; j < 8; ++j) {
      float dx = x1[j] - v.x, dy = y1[j] - v.y, dz = z1[j] - v.z;
      float d2 = __builtin_fmaf(dx, dx, __builtin_fmaf(dy, dy, dz * dz));
      acc[j] = __builtin_fmaf(fast_sqrt(d2), v.w, acc[j]);
    }
  }
#pragma unroll
  for (int j = 0; j < 8; ++j) {
    acc[j] += __shfl_xor(acc[j], 2, 64);
    acc[j] += __shfl_xor(acc[j], 4, 64);
    acc[j] += __shfl_xor(acc[j], 8, 64);
    acc[j] += __shfl_xor(acc[j], 16, 64);
    acc[j] += __shfl_xor(acc[j], 32, 64);
  }
  if (lane < 2) {
#pragma unroll
    for (int j = 0; j < 8; ++j) sRed[(rg * 8 + j) * 4 + wave] = acc[j];
  }
  __syncthreads();
  if (tid < ROWS) {
    float C = sRed[tid * 4] + sRed[tid * 4 + 1] + sRed[tid * 4 + 2] +
              sRed[tid * 4 + 3];
    sCost[tid] = rowscale[(size_t)b * NPTS + t0 + tid] * C;
  }
  __syncthreads();
  if (tid == 0) {
    float t = 0.0f;
#pragma unroll
    for (int i = 0; i < ROWS; ++i) t += sCost[i];
    atomicAdd(out + b, t);
  }
}

// ---------------------------------------------------------------------------
static void launch_fallback(const float* xyz1, const float* xyz2, float* out,
                            float* ws, hipStream_t stream) {
  const int BN = BATCH * NPTS, BM = BATCH * MPTS;
  float* remainL  = ws;                   // BN
  float* rowscale = ws + BN;              // BN
  float* rrA      = ws + 2 * BN;          // BM
  float* rrB      = ws + 2 * BN + BM;     // BM
  float* t1b      = ws + 2 * BN + 2 * BM; // 3*BM
  float* t9       = ws + 2 * BN + 5 * BM; // BATCH

  const float levels[9] = {-16384.f, -4096.f, -1024.f, -256.f, -64.f,
                           -16.f,    -4.f,    -1.f,    -0.25f};
  dim3 grid(BATCH * (NPTS / ROWS));

  hipMemsetAsync(t1b, 0, (size_t)BM * sizeof(float), stream);
  emd_A0_kernel<<<grid, BLOCK, 0, stream>>>(
      xyz1, xyz2, rowscale, out, t9, t1b, t1b + BM,
      sqrtf(-levels[0] * LOG2E));
  for (int l = 0; l < 9; ++l) {
    float kB = sqrtf(-levels[l] * LOG2E);
    float kA = 0.5f * kB;
    float* cur = t1b + (size_t)(l % 3) * BM;
    float* nxt = t1b + (size_t)((l + 1) % 3) * BM;
    float* zer = t1b + (size_t)((l + 2) % 3) * BM;
    float* rin = (l % 2 == 0) ? rrA : rrB;
    float* rou = (l % 2 == 0) ? rrB : rrA;
    if (l == 0) {
      emd_CA_kernel<true, false><<<grid, BLOCK, 0, stream>>>(
          xyz1, xyz2, rowscale, remainL, rin, rou, cur, nxt, zer, out, t9,
          kA, 1.0f / kA);
    } else if (l < 8) {
      emd_CA_kernel<false, false><<<grid, BLOCK, 0, stream>>>(
          xyz1, xyz2, rowscale, remainL, rin, rou, cur, nxt, zer, out, t9,
          kA, 1.0f / kA);
    } else {
      emd_CA_kernel<false, true><<<grid, BLOCK, 0, stream>>>(
          xyz1, xyz2, rowscale, remainL, rin, rou, cur, nxt, zer, out, t9,
          kB, 1.0f / kB);
    }
  }
  emd_C9_kernel<<<grid, BLOCK, 0, stream>>>(xyz1, xyz2, rowscale, rrB, t9, out);
}

extern "C" void kernel_launch(void* const* d_in, const int* in_sizes, int n_in,
                              void* d_out, int out_size, void* d_ws, size_t ws_size,
                              hipStream_t stream) {
  const float* xyz1 = (const float*)d_in[0];
  const float* xyz2 = (const float*)d_in[1];
  float* out = (float*)d_out;
  float* ws = (float*)d_ws;

  // mode: -1 unknown, 1 cooperative, 0 fallback. Decided once (host-only
  // queries; graph-capture safe).
  static int mode = -1;
  if (mode < 0) {
    int dev = 0;
    hipGetDevice(&dev);
    hipDeviceProp_t prop;
    int maxb = 0;
    hipError_t e1 = hipGetDeviceProperties(&prop, dev);
    hipError_t e2 = hipOccupancyMaxActiveBlocksPerMultiprocessor(
        &maxb, (const void*)emd_fused_kernel, BLOCK, 0);
    mode = (e1 == hipSuccess && e2 == hipSuccess && prop.cooperativeLaunch &&
            maxb * prop.multiProcessorCount >= BATCH * (NPTS / ROWS)) ? 1 : 0;
  }

  if (mode == 1) {
    const int BM = BATCH * MPTS;
    float* rrA = ws;                      // BM
    float* rrB = ws + BM;                 // BM
    float* t1b = ws + 2 * BM;             // 3*BM
    float* t9  = ws + 5 * BM;             // BATCH
    void* args[] = {(void*)&xyz1, (void*)&xyz2, (void*)&out, (void*)&t1b,
                    (void*)&rrA, (void*)&rrB, (void*)&t9};
    hipError_t err = hipLaunchCooperativeKernel(
        (const void*)emd_fused_kernel, dim3(BATCH * (NPTS / ROWS)),
        dim3(BLOCK), args, 0, stream);
    if (err == hipSuccess) return;
    mode = 0;  // permanent fallback
  }
  launch_fallback(xyz1, xyz2, out, ws, stream);
}